// Round 8
// baseline (518.694 us; speedup 1.0000x reference)
//
#include <hip/hip_runtime.h>

// ---------------------------------------------------------------------------
// CrossAttentionMM on MI355X (gfx950), bf16 MFMA pipeline.
// B=4, SQ=4096, SKV=1024, QDIM=1024, CDIM=768, H=16, D=64, INNER=1024.
// R13: attn v8 — NO LDS, NO barriers. K/V (256 KB/head, 16 MB total) is
// L2-resident; each wave reads its MFMA fragments directly from global (L2)
// with the same unswizzled per-lane addresses it previously read from LDS.
// Kills the per-iteration __syncthreads convoy (the ~40% idle in R9-R12),
// the 8.4M bank conflicts, and all staging instructions. Waves fully
// independent; grid (32,64) x 256 thr, launch_bounds(256,4) (128 VGPR cap).
// PV stays K=32 f16 with ds_bpermute octet assembly (LDS pipe now idle).
// GEMMs (256^2 8-phase) / cvt / twt unchanged.
// ---------------------------------------------------------------------------

typedef unsigned short u16;
typedef unsigned int u32;
typedef __bf16 bf16x8 __attribute__((ext_vector_type(8)));
typedef float float4v __attribute__((ext_vector_type(4)));
typedef _Float16 half4 __attribute__((ext_vector_type(4)));
typedef _Float16 half8 __attribute__((ext_vector_type(8)));
typedef _Float16 half2v __attribute__((ext_vector_type(2)));
typedef u32 u32x2 __attribute__((ext_vector_type(2)));
typedef u32 u32x4 __attribute__((ext_vector_type(4)));
typedef __attribute__((address_space(1))) void as1_void;
typedef __attribute__((address_space(3))) void as3_void;

__device__ __forceinline__ u16 f2bf(float f) {
  unsigned u = __float_as_uint(f);
  u += 0x7FFF + ((u >> 16) & 1);   // RTNE
  return (u16)(u >> 16);
}

// async global->LDS, 16B per lane. LDS dest = wave-uniform base + lane*16.
__device__ __forceinline__ void async16(const u16* g, u16* l) {
  __builtin_amdgcn_global_load_lds((as1_void*)(void*)g, (as3_void*)l, 16, 0, 0);
}

// gfx9 waitcnt imm: vmcnt[3:0]=imm[3:0], exp=imm[6:4], lgkm=imm[11:8], vmcnt[5:4]=imm[15:14]
#define WAITCNT_VM8 0xF78   // vmcnt(8), lgkm/exp no-wait
#define WAITCNT_VM4 0xF74   // vmcnt(4)
#define WAITCNT_VM0 0xF70   // vmcnt(0)

// ---------------- fp32 -> bf16 cast: x then ctx, one launch ----------------
__global__ void cvt_kernel(const float* __restrict__ x, u16* __restrict__ xbf,
                           const float* __restrict__ ctx, u16* __restrict__ ctxbf) {
  int i = blockIdx.x * 256 + threadIdx.x;
  const float* in; u16* out; int j;
  if (i < 4194304) { in = x; out = xbf; j = i; }
  else if (i < 4980736) { in = ctx; out = ctxbf; j = i - 4194304; }
  else return;
  float4 v = ((const float4*)in)[j];
  ushort4 o;
  o.x = f2bf(v.x); o.y = f2bf(v.y); o.z = f2bf(v.z); o.w = f2bf(v.w);
  ((ushort4*)out)[j] = o;
}

// ---------------- all 4 weights: W[K,N] fp32 -> Wt[N,K] bf16, one launch ----
__global__ void twt_kernel(const float* __restrict__ Wq, const float* __restrict__ Wk,
                           const float* __restrict__ Wv, const float* __restrict__ Wo,
                           u16* __restrict__ WqT, u16* __restrict__ WkT,
                           u16* __restrict__ WvT, u16* __restrict__ WoT) {
  __shared__ u16 t[32][33];
  int z = blockIdx.z;
  const float* W = z == 0 ? Wq : z == 1 ? Wk : z == 2 ? Wv : Wo;
  u16* Wt = z == 0 ? WqT : z == 1 ? WkT : z == 2 ? WvT : WoT;
  int Kd = (z == 1 || z == 2) ? 768 : 1024;
  int k0 = blockIdx.y * 32;
  if (k0 >= Kd) return;
  int tx = threadIdx.x, ty = threadIdx.y;
  int n0 = blockIdx.x * 32;
#pragma unroll
  for (int i = 0; i < 4; i++)
    t[ty + i * 8][tx] = f2bf(W[(size_t)(k0 + ty + i * 8) * 1024 + n0 + tx]);
  __syncthreads();
#pragma unroll
  for (int i = 0; i < 4; i++)
    Wt[(size_t)(n0 + ty + i * 8) * Kd + k0 + tx] = t[tx][ty + i * 8];
}

// ---------------------------------------------------------------------------
// 256x256 / BK=64 / 8-wave 8-phase GEMM core (C = A * Bt^T), bf16 inputs.
// ---------------------------------------------------------------------------

__device__ __forceinline__ void ld_a4(const u16 (*Lp)[256][8], int rbase, int quad,
                                      int l15, bf16x8 a[4][2]) {
#pragma unroll
  for (int mi = 0; mi < 4; mi++)
#pragma unroll
    for (int ks = 0; ks < 2; ks++)
      a[mi][ks] = *(const bf16x8*)&Lp[ks * 4 + quad][rbase + mi * 16 + l15][0];
}

__device__ __forceinline__ void ld_b2(const u16 (*Lp)[256][8], int rbase, int quad,
                                      int l15, bf16x8 b[2][2]) {
#pragma unroll
  for (int ni = 0; ni < 2; ni++)
#pragma unroll
    for (int ks = 0; ks < 2; ks++)
      b[ni][ks] = *(const bf16x8*)&Lp[ks * 4 + quad][rbase + ni * 16 + l15][0];
}

__device__ __forceinline__ void mm16(bf16x8 a[4][2], bf16x8 b[2][2],
                                     float4v acc[8][4], int mh, int nh) {
  __builtin_amdgcn_s_setprio(1);
#pragma unroll
  for (int mi = 0; mi < 4; mi++)
#pragma unroll
    for (int ni = 0; ni < 2; ni++)
#pragma unroll
      for (int ks = 0; ks < 2; ks++)
        acc[mh * 4 + mi][nh * 2 + ni] = __builtin_amdgcn_mfma_f32_16x16x32_bf16(
            a[mi][ks], b[ni][ks], acc[mh * 4 + mi][nh * 2 + ni], 0, 0, 0);
  __builtin_amdgcn_s_setprio(0);
}

__device__ __forceinline__ void gemm256_core(const u16* __restrict__ A,
                                             const u16* __restrict__ Bt, int K,
                                             int m0, int n0, float4v acc[8][4]) {
  __shared__ __align__(16) u16 L[2][2][8][256][8];   // 128 KiB
  int tid = threadIdx.x;
  int w = tid >> 6, lane = tid & 63;
  int l15 = lane & 15, quad = lane >> 4;
  int wm = (w >> 2) * 128, wn = (w & 3) * 64;

  int c0 = 2 * w, c1 = 2 * w + 1;
  int kc0 = c0 & 7, mb0 = (c0 >> 3) * 64;
  int kc1 = c1 & 7, mb1 = (c1 >> 3) * 64;
  const u16* pA0 = A + (size_t)(m0 + mb0 + lane) * K + kc0 * 8;
  const u16* pA1 = A + (size_t)(m0 + mb1 + lane) * K + kc1 * 8;
  const u16* pB0 = Bt + (size_t)(n0 + mb0 + lane) * K + kc0 * 8;
  const u16* pB1 = Bt + (size_t)(n0 + mb1 + lane) * K + kc1 * 8;
  size_t hs = (size_t)128 * K;   // +128 rows (u16 elems)

#define STG_A(buf, t)                                                          \
  do {                                                                         \
    const u16* s0 = pA0 + (size_t)(t) * 64;                                    \
    const u16* s1 = pA1 + (size_t)(t) * 64;                                    \
    async16(s0, &L[buf][0][kc0][mb0][0]);                                      \
    async16(s1, &L[buf][0][kc1][mb1][0]);                                      \
    async16(s0 + hs, &L[buf][0][kc0][128 + mb0][0]);                           \
    async16(s1 + hs, &L[buf][0][kc1][128 + mb1][0]);                           \
  } while (0)
#define STG_B(buf, t)                                                          \
  do {                                                                         \
    const u16* s0 = pB0 + (size_t)(t) * 64;                                    \
    const u16* s1 = pB1 + (size_t)(t) * 64;                                    \
    async16(s0, &L[buf][1][kc0][mb0][0]);                                      \
    async16(s1, &L[buf][1][kc1][mb1][0]);                                      \
    async16(s0 + hs, &L[buf][1][kc0][128 + mb0][0]);                           \
    async16(s1 + hs, &L[buf][1][kc1][128 + mb1][0]);                           \
  } while (0)

  // prologue: tiles 0 -> buf0, 1 -> buf1 (16 loads/thread outstanding)
  STG_A(0, 0); STG_B(0, 0);
  STG_A(1, 1); STG_B(1, 1);
  __builtin_amdgcn_s_waitcnt(WAITCNT_VM8);   // tile 0 landed; tile 1 in flight
  __builtin_amdgcn_s_barrier();

  bf16x8 a[4][2], b0[2][2], b1[2][2];
  int I = K >> 7;                            // 2 K-tiles (of 64) per iteration
  for (int i = 0; i < I; ++i) {
    int st = (i + 1 < I);
    // ================= buf0 : K-tile 2i =================
    // PH1
    ld_a4(L[0][0], wm, quad, l15, a);
    ld_b2(L[0][1], wn, quad, l15, b0);
    if (i > 0) STG_B(1, 2 * i + 1);          // buf1 B last read PH6 of prev iter
    __builtin_amdgcn_s_barrier();
    mm16(a, b0, acc, 0, 0);
    __builtin_amdgcn_s_barrier();
    // PH2
    ld_b2(L[0][1], wn + 32, quad, l15, b1);
    __builtin_amdgcn_s_barrier();
    mm16(a, b1, acc, 0, 1);
    __builtin_amdgcn_s_barrier();
    // PH3
    ld_a4(L[0][0], wm + 64, quad, l15, a);
    __builtin_amdgcn_s_barrier();
    mm16(a, b1, acc, 1, 1);
    __builtin_amdgcn_s_barrier();
    // PH4
    if (st) STG_A(0, 2 * i + 2);             // buf0 A last read PH3
    __builtin_amdgcn_s_barrier();
    mm16(a, b0, acc, 1, 0);
    if (st) __builtin_amdgcn_s_waitcnt(WAITCNT_VM4);  // tile 2i+1 fully landed
    else    __builtin_amdgcn_s_waitcnt(WAITCNT_VM0);
    __builtin_amdgcn_s_barrier();
    // ================= buf1 : K-tile 2i+1 =================
    // PH5
    ld_a4(L[1][0], wm, quad, l15, a);
    ld_b2(L[1][1], wn, quad, l15, b0);
    if (st) STG_B(0, 2 * i + 2);             // buf0 B last read PH2
    __builtin_amdgcn_s_barrier();
    mm16(a, b0, acc, 0, 0);
    __builtin_amdgcn_s_barrier();
    // PH6
    ld_b2(L[1][1], wn + 32, quad, l15, b1);
    __builtin_amdgcn_s_barrier();
    mm16(a, b1, acc, 0, 1);
    __builtin_amdgcn_s_barrier();
    // PH7
    ld_a4(L[1][0], wm + 64, quad, l15, a);
    __builtin_amdgcn_s_barrier();
    mm16(a, b1, acc, 1, 1);
    __builtin_amdgcn_s_barrier();
    // PH8
    if (st) STG_A(1, 2 * i + 3);             // buf1 A last read PH7
    __builtin_amdgcn_s_barrier();
    mm16(a, b0, acc, 1, 0);
    if (st) __builtin_amdgcn_s_waitcnt(WAITCNT_VM4);  // tile 2i+2 fully landed
    __builtin_amdgcn_s_barrier();
  }
#undef STG_A
#undef STG_B
}

// ---------------- fused QKV projection GEMM (bx-partitioned, 256^2 tiles) --
__global__ __launch_bounds__(512, 2) void qkv_gemm8(
    const u16* __restrict__ xbf, const u16* __restrict__ ctxbf,
    const u16* __restrict__ WqT, const u16* __restrict__ WkT, const u16* __restrict__ WvT,
    u16* __restrict__ Qb, u16* __restrict__ Kbuf, u16* __restrict__ Vtb, float qscale) {
  int bx = blockIdx.x;
  const u16* A; const u16* Bt; u16* C; int K, mode, m0, n0; float scale;
  if (bx < 256)      { int t = bx;       A = xbf;   Bt = WqT; C = Qb;   K = 1024; mode = 0; scale = qscale; m0 = (t >> 2) * 256; n0 = (t & 3) * 256; }
  else if (bx < 320) { int t = bx - 256; A = ctxbf; Bt = WkT; C = Kbuf; K = 768;  mode = 0; scale = 1.0f;   m0 = (t >> 2) * 256; n0 = (t & 3) * 256; }
  else               { int t = bx - 320; A = ctxbf; Bt = WvT; C = Vtb;  K = 768;  mode = 2; scale = 1.0f;   m0 = (t >> 2) * 256; n0 = (t & 3) * 256; }

  float4v acc[8][4] = {};
  gemm256_core(A, Bt, K, m0, n0, acc);

  int tid = threadIdx.x;
  int w = tid >> 6, lane = tid & 63;
  int l15 = lane & 15, quad = lane >> 4;
  int wm = (w >> 2) * 128, wn = (w & 3) * 64;

  if (mode == 0) {
#pragma unroll
    for (int mi = 0; mi < 8; mi++) {
      int rowb = m0 + wm + mi * 16 + quad * 4;
#pragma unroll
      for (int ni = 0; ni < 4; ni++) {
        int col = n0 + wn + ni * 16 + l15;
#pragma unroll
        for (int r = 0; r < 4; r++)
          C[(size_t)(rowb + r) * 1024 + col] = f2bf(acc[mi][ni][r] * scale);
      }
    }
  } else {
#pragma unroll
    for (int mi = 0; mi < 8; mi++) {
      int rowb = m0 + wm + mi * 16 + quad * 4;
#pragma unroll
      for (int ni = 0; ni < 4; ni++) {
        int col = n0 + wn + ni * 16 + l15;
        int hh = col >> 6, dd = col & 63;
#pragma unroll
        for (int r = 0; r < 4; r++) {
          int rr = rowb + r;
          int b = rr >> 10, skv = rr & 1023;
          _Float16 hv = (_Float16)acc[mi][ni][r];
          C[((((size_t)b * 16 + hh) * 64 + dd) << 10) + skv] = __builtin_bit_cast(u16, hv);
        }
      }
    }
  }
}

// ---------------- output projection: out = attn*WoT^T + bo (fp32, 256^2) ---
__global__ __launch_bounds__(512, 2) void gemm_bt8(
    const u16* __restrict__ A, const u16* __restrict__ Bt,
    float* __restrict__ C, const float* __restrict__ bias) {
  int bx = blockIdx.x;
  int m0 = (bx >> 2) * 256, n0 = (bx & 3) * 256;

  float4v acc[8][4] = {};
  gemm256_core(A, Bt, 1024, m0, n0, acc);

  int tid = threadIdx.x;
  int w = tid >> 6, lane = tid & 63;
  int l15 = lane & 15, quad = lane >> 4;
  int wm = (w >> 2) * 128, wn = (w & 3) * 64;

#pragma unroll
  for (int mi = 0; mi < 8; mi++) {
    int rowb = m0 + wm + mi * 16 + quad * 4;
#pragma unroll
    for (int ni = 0; ni < 4; ni++) {
      int col = n0 + wn + ni * 16 + l15;
      float bv = bias[col];
#pragma unroll
      for (int r = 0; r < 4; r++)
        C[(size_t)(rowb + r) * 1024 + col] = acc[mi][ni][r] + bv;
    }
  }
}

// ---------------- attention v8: per (b,h), O = softmax(Q K^T) V -------------
// grid (SQ/128, B*H), block 256 (4 waves, 32 q each), launch_bounds(256,4).
// NO LDS, NO barriers: K/V fragments read directly from global (L2-resident,
// 256 KB/head). Same per-lane fragment addresses as the LDS version, minus
// the swizzle. Each wave fully independent; TLP (16 waves/CU) + compiler
// load hoisting hide L2 latency. PV/rowsum = K=32 f16 MFMAs; P octet via
// 8 ds_bpermute + 4 selects (LDS pipe is otherwise idle).
__global__ __launch_bounds__(256, 4) void attn_kernel(
    const u16* __restrict__ Q, const u16* __restrict__ Kb,
    const u16* __restrict__ Vt, u16* __restrict__ Oout) {
  int tid = threadIdx.x, w = tid >> 6, lane = tid & 63;
  int l15 = lane & 15, quad = lane >> 4;
  int bh = blockIdx.y, b = bh >> 4, h = bh & 15;
  int q0 = blockIdx.x * 128 + w * 32;

  const u16* Qbase = Q + ((size_t)(b * 4096 + q0)) * 1024 + h * 64;
  // K fragment pointer: kv-row l15 (+ sub*16 + it*64), d-col quad*8 (+ c*32)
  const u16* kp = Kb + ((size_t)b << 20) + h * 64 + (size_t)l15 * 1024 + quad * 8;
  // V fragment pointer: d-row l15 (+ dt*16), kv-col quad*8 (+ s*32 + it*64)
  const u16* vp = Vt + ((size_t)bh << 16) + (size_t)l15 * 1024 + quad * 8;

  // Q B-fragments, resident whole kernel: [qt][c], lane: q=qt*16+l15, d=c*32+quad*8..+7
  bf16x8 qf[2][2];
#pragma unroll
  for (int qt = 0; qt < 2; qt++)
#pragma unroll
    for (int c = 0; c < 2; c++)
      qf[qt][c] = *(const bf16x8*)(Qbase + (size_t)(qt * 16 + l15) * 1024 + c * 32 + quad * 8);

  float4v o[2][4] = {};     // [qt][dt] O^T accumulators (C-layout)
  float4v osum[2] = {};     // row sums via ones-MFMA (every lane gets its q's sum)
  const half8 ones8 = {(_Float16)1.0f, (_Float16)1.0f, (_Float16)1.0f, (_Float16)1.0f,
                       (_Float16)1.0f, (_Float16)1.0f, (_Float16)1.0f, (_Float16)1.0f};

  // octet-exchange lane indices (bytes for ds_bpermute)
  int idx_lo = (((quad & 1) << 5) + l15) << 2;     // src lane (quad&1)*32+l15
  int idx_hi = idx_lo + 64;                        // +16 lanes
  bool useb = (quad & 2) != 0;

  for (int it = 0; it < 16; ++it) {
    const u16* kit = kp + (size_t)it * 65536;      // +64 kv rows (x1024)
    const u16* vit = vp + it * 64;                 // +64 along skv
#pragma unroll
    for (int s = 0; s < 2; ++s) {        // pair of 16-kv sub-tiles
      half4 pp[2][2];                    // [half-of-pair][qt], static-indexed
#pragma unroll
      for (int hp = 0; hp < 2; ++hp) {
        int sub = s * 2 + hp;
        const u16* ks = kit + sub * 16384;         // +16 kv rows
        // S^T tile: rows kv=sub*16+quad*4+r, cols q=qt*16+l15
        float4v sv[2] = {{0.f, 0.f, 0.f, 0.f}, {0.f, 0.f, 0.f, 0.f}};
        __builtin_amdgcn_s_setprio(1);
#pragma unroll
        for (int c = 0; c < 2; c++) {
          bf16x8 kf = *(const bf16x8*)(ks + c * 32);
#pragma unroll
          for (int qt = 0; qt < 2; qt++)
            sv[qt] = __builtin_amdgcn_mfma_f32_16x16x32_bf16(kf, qf[qt][c], sv[qt], 0, 0, 0);
        }
        __builtin_amdgcn_s_setprio(0);
        // P = exp2(S') (log2e folded into Q scale); pack f16
#pragma unroll
        for (int qt = 0; qt < 2; qt++) {
          float e0 = exp2f(sv[qt][0]), e1 = exp2f(sv[qt][1]);
          float e2 = exp2f(sv[qt][2]), e3 = exp2f(sv[qt][3]);
          half2v p01 = __builtin_bit_cast(half2v, __builtin_amdgcn_cvt_pkrtz(e0, e1));
          half2v p23 = __builtin_bit_cast(half2v, __builtin_amdgcn_cvt_pkrtz(e2, e3));
          pp[hp][qt] = __builtin_shufflevector(p01, p23, 0, 1, 2, 3);
        }
      }
      // octet assembly: lane needs kv = quad*8..+7 of this 32-kv pair
      half8 p8s[2];
#pragma unroll
      for (int qt = 0; qt < 2; qt++) {
        u32x2 a2 = __builtin_bit_cast(u32x2, pp[0][qt]);
        u32x2 b2 = __builtin_bit_cast(u32x2, pp[1][qt]);
        int al0 = __builtin_amdgcn_ds_bpermute(idx_lo, (int)a2[0]);
        int ah0 = __builtin_amdgcn_ds_bpermute(idx_lo, (int)a2[1]);
        int al1 = __builtin_amdgcn_ds_bpermute(idx_hi, (int)a2[0]);
        int ah1 = __builtin_amdgcn_ds_bpermute(idx_hi, (int)a2[1]);
        int bl0 = __builtin_amdgcn_ds_bpermute(idx_lo, (int)b2[0]);
        int bh0 = __builtin_amdgcn_ds_bpermute(idx_lo, (int)b2[1]);
        int bl1 = __builtin_amdgcn_ds_bpermute(idx_hi, (int)b2[0]);
        int bh1 = __builtin_amdgcn_ds_bpermute(idx_hi, (int)b2[1]);
        u32x4 od;
        od[0] = (u32)(useb ? bl0 : al0);
        od[1] = (u32)(useb ? bh0 : ah0);
        od[2] = (u32)(useb ? bl1 : al1);
        od[3] = (u32)(useb ? bh1 : ah1);
        half8 p8 = __builtin_bit_cast(half8, od);
        p8s[qt] = p8;
        osum[qt] = __builtin_amdgcn_mfma_f32_16x16x32_f16(ones8, p8, osum[qt], 0, 0, 0);
      }
      // O^T += V^T * P^T  (K=32 f16; V octet read straight from global/L2)
      __builtin_amdgcn_s_setprio(1);
#pragma unroll
      for (int dt = 0; dt < 4; dt++) {
        half8 vf = *(const half8*)(vit + (size_t)dt * 16384 + s * 32);
#pragma unroll
        for (int qt = 0; qt < 2; qt++)
          o[qt][dt] = __builtin_amdgcn_mfma_f32_16x16x32_f16(vf, p8s[qt], o[qt][dt], 0, 0, 0);
      }
      __builtin_amdgcn_s_setprio(0);
    }
  }

#pragma unroll
  for (int qt = 0; qt < 2; qt++) {
    float inv = 1.0f / osum[qt][0];   // all rows of the ones-product are the q-col sum
    u16* Ob = Oout + ((size_t)(b * 4096 + q0 + qt * 16 + l15)) * 1024 + h * 64 + quad * 4;
#pragma unroll
    for (int dt = 0; dt < 4; dt++) {
      ushort4 pk;
      pk.x = f2bf(o[qt][dt][0] * inv);
      pk.y = f2bf(o[qt][dt][1] * inv);
      pk.z = f2bf(o[qt][dt][2] * inv);
      pk.w = f2bf(o[qt][dt][3] * inv);
      *(ushort4*)(Ob + dt * 16) = pk;
    }
  }
}

// ---------------------------------------------------------------------------
extern "C" void kernel_launch(void* const* d_in, const int* in_sizes, int n_in,
                              void* d_out, int out_size, void* d_ws, size_t ws_size,
                              hipStream_t stream) {
  const float* x   = (const float*)d_in[0];
  const float* ctx = (const float*)d_in[1];
  const float* Wq  = (const float*)d_in[2];
  const float* Wk  = (const float*)d_in[3];
  const float* Wv  = (const float*)d_in[4];
  const float* Wo  = (const float*)d_in[5];
  const float* bo  = (const float*)d_in[6];
  float* out = (float*)d_out;

  u16* ws    = (u16*)d_ws;
  u16* xbf   = ws;                  // 16777216 elems (reused as attn_out)
  u16* ctxbf = xbf + 16777216;      // 3145728
  u16* WqT   = ctxbf + 3145728;     // 1048576
  u16* WkT   = WqT + 1048576;       // 786432
  u16* WvT   = WkT + 786432;        // 786432
  u16* WoT   = WvT + 786432;        // 1048576
  u16* Qb    = WoT + 1048576;       // 16777216
  u16* Kbuf  = Qb + 16777216;       // 4194304
  u16* Vtb   = Kbuf + 4194304;      // 4194304 (f16)  -> total ~93 MB
  if (ws_size < (size_t)48758784 * 2) return;  // workspace too small: clean fail

  cvt_kernel<<<19456, 256, 0, stream>>>(x, xbf, ctx, ctxbf);
  twt_kernel<<<dim3(32, 32, 4), dim3(32, 8), 0, stream>>>(Wq, Wk, Wv, Wo, WqT, WkT, WvT, WoT);
  // 256 Q-blocks + 64 K-blocks + 64 V-blocks, 512 threads, 8-phase schedule
  qkv_gemm8<<<dim3(384), dim3(512), 0, stream>>>(xbf, ctxbf, WqT, WkT, WvT,
                                                 Qb, Kbuf, Vtb, 0.18033688011112042f);
  // attention -> attn_out (bf16, [b, sq, h*64+d]), reusing xbf
  attn_kernel<<<dim3(32, 64), dim3(256), 0, stream>>>(Qb, Kbuf, Vtb, xbf);
  // out = attn_out*Wo + bo (fp32), 64x4 tiles of 256^2
  gemm_bt8<<<dim3(256), dim3(512), 0, stream>>>(xbf, WoT, out, bo);
}

// Round 9
// 378.281 us; speedup vs baseline: 1.3712x; 1.3712x over previous
//
#include <hip/hip_runtime.h>

// ---------------------------------------------------------------------------
// CrossAttentionMM on MI355X (gfx950), bf16 MFMA pipeline.
// B=4, SQ=4096, SKV=1024, QDIM=1024, CDIM=768, H=16, D=64, INNER=1024.
// R14: attn v9 = R10 structure (best measured, 119us) with KVBLK 64 -> 128:
// 8 iterations instead of 16. R7-R12 showed time is pinned ~120us across
// MFMA-count/occupancy/order changes -> per-iteration fixed cost (sync drain
// + staging + convoy) dominates; halving iteration count amortizes it 2x.
// LDS 64KB (2 blocks/CU, residency unchanged). K rows keep 3-bit XOR swizzle;
// V rows (now 128 kv wide, 16 chunks) use 4-bit XOR c^(d&15), applied on the
// pre-swizzled global source AND the read offset (both-sides rule).
// GEMMs (256^2 8-phase) / cvt / twt unchanged. R13's no-LDS reverted (258us:
// lost reuse amortization, 4x L2 request traffic).
// ---------------------------------------------------------------------------

typedef unsigned short u16;
typedef unsigned int u32;
typedef __bf16 bf16x8 __attribute__((ext_vector_type(8)));
typedef float float4v __attribute__((ext_vector_type(4)));
typedef _Float16 half4 __attribute__((ext_vector_type(4)));
typedef _Float16 half2v __attribute__((ext_vector_type(2)));
typedef __attribute__((address_space(1))) void as1_void;
typedef __attribute__((address_space(3))) void as3_void;

__device__ __forceinline__ u16 f2bf(float f) {
  unsigned u = __float_as_uint(f);
  u += 0x7FFF + ((u >> 16) & 1);   // RTNE
  return (u16)(u >> 16);
}

// async global->LDS, 16B per lane. LDS dest = wave-uniform base + lane*16.
__device__ __forceinline__ void async16(const u16* g, u16* l) {
  __builtin_amdgcn_global_load_lds((as1_void*)(void*)g, (as3_void*)l, 16, 0, 0);
}

// gfx9 waitcnt imm: vmcnt[3:0]=imm[3:0], exp=imm[6:4], lgkm=imm[11:8], vmcnt[5:4]=imm[15:14]
#define WAITCNT_VM8 0xF78   // vmcnt(8), lgkm/exp no-wait
#define WAITCNT_VM4 0xF74   // vmcnt(4)
#define WAITCNT_VM0 0xF70   // vmcnt(0)

// ---------------- fp32 -> bf16 cast: x then ctx, one launch ----------------
__global__ void cvt_kernel(const float* __restrict__ x, u16* __restrict__ xbf,
                           const float* __restrict__ ctx, u16* __restrict__ ctxbf) {
  int i = blockIdx.x * 256 + threadIdx.x;
  const float* in; u16* out; int j;
  if (i < 4194304) { in = x; out = xbf; j = i; }
  else if (i < 4980736) { in = ctx; out = ctxbf; j = i - 4194304; }
  else return;
  float4 v = ((const float4*)in)[j];
  ushort4 o;
  o.x = f2bf(v.x); o.y = f2bf(v.y); o.z = f2bf(v.z); o.w = f2bf(v.w);
  ((ushort4*)out)[j] = o;
}

// ---------------- all 4 weights: W[K,N] fp32 -> Wt[N,K] bf16, one launch ----
__global__ void twt_kernel(const float* __restrict__ Wq, const float* __restrict__ Wk,
                           const float* __restrict__ Wv, const float* __restrict__ Wo,
                           u16* __restrict__ WqT, u16* __restrict__ WkT,
                           u16* __restrict__ WvT, u16* __restrict__ WoT) {
  __shared__ u16 t[32][33];
  int z = blockIdx.z;
  const float* W = z == 0 ? Wq : z == 1 ? Wk : z == 2 ? Wv : Wo;
  u16* Wt = z == 0 ? WqT : z == 1 ? WkT : z == 2 ? WvT : WoT;
  int Kd = (z == 1 || z == 2) ? 768 : 1024;
  int k0 = blockIdx.y * 32;
  if (k0 >= Kd) return;
  int tx = threadIdx.x, ty = threadIdx.y;
  int n0 = blockIdx.x * 32;
#pragma unroll
  for (int i = 0; i < 4; i++)
    t[ty + i * 8][tx] = f2bf(W[(size_t)(k0 + ty + i * 8) * 1024 + n0 + tx]);
  __syncthreads();
#pragma unroll
  for (int i = 0; i < 4; i++)
    Wt[(size_t)(n0 + ty + i * 8) * Kd + k0 + tx] = t[tx][ty + i * 8];
}

// ---------------------------------------------------------------------------
// 256x256 / BK=64 / 8-wave 8-phase GEMM core (C = A * Bt^T), bf16 inputs.
// ---------------------------------------------------------------------------

__device__ __forceinline__ void ld_a4(const u16 (*Lp)[256][8], int rbase, int quad,
                                      int l15, bf16x8 a[4][2]) {
#pragma unroll
  for (int mi = 0; mi < 4; mi++)
#pragma unroll
    for (int ks = 0; ks < 2; ks++)
      a[mi][ks] = *(const bf16x8*)&Lp[ks * 4 + quad][rbase + mi * 16 + l15][0];
}

__device__ __forceinline__ void ld_b2(const u16 (*Lp)[256][8], int rbase, int quad,
                                      int l15, bf16x8 b[2][2]) {
#pragma unroll
  for (int ni = 0; ni < 2; ni++)
#pragma unroll
    for (int ks = 0; ks < 2; ks++)
      b[ni][ks] = *(const bf16x8*)&Lp[ks * 4 + quad][rbase + ni * 16 + l15][0];
}

__device__ __forceinline__ void mm16(bf16x8 a[4][2], bf16x8 b[2][2],
                                     float4v acc[8][4], int mh, int nh) {
  __builtin_amdgcn_s_setprio(1);
#pragma unroll
  for (int mi = 0; mi < 4; mi++)
#pragma unroll
    for (int ni = 0; ni < 2; ni++)
#pragma unroll
      for (int ks = 0; ks < 2; ks++)
        acc[mh * 4 + mi][nh * 2 + ni] = __builtin_amdgcn_mfma_f32_16x16x32_bf16(
            a[mi][ks], b[ni][ks], acc[mh * 4 + mi][nh * 2 + ni], 0, 0, 0);
  __builtin_amdgcn_s_setprio(0);
}

__device__ __forceinline__ void gemm256_core(const u16* __restrict__ A,
                                             const u16* __restrict__ Bt, int K,
                                             int m0, int n0, float4v acc[8][4]) {
  __shared__ __align__(16) u16 L[2][2][8][256][8];   // 128 KiB
  int tid = threadIdx.x;
  int w = tid >> 6, lane = tid & 63;
  int l15 = lane & 15, quad = lane >> 4;
  int wm = (w >> 2) * 128, wn = (w & 3) * 64;

  int c0 = 2 * w, c1 = 2 * w + 1;
  int kc0 = c0 & 7, mb0 = (c0 >> 3) * 64;
  int kc1 = c1 & 7, mb1 = (c1 >> 3) * 64;
  const u16* pA0 = A + (size_t)(m0 + mb0 + lane) * K + kc0 * 8;
  const u16* pA1 = A + (size_t)(m0 + mb1 + lane) * K + kc1 * 8;
  const u16* pB0 = Bt + (size_t)(n0 + mb0 + lane) * K + kc0 * 8;
  const u16* pB1 = Bt + (size_t)(n0 + mb1 + lane) * K + kc1 * 8;
  size_t hs = (size_t)128 * K;   // +128 rows (u16 elems)

#define STG_A(buf, t)                                                          \
  do {                                                                         \
    const u16* s0 = pA0 + (size_t)(t) * 64;                                    \
    const u16* s1 = pA1 + (size_t)(t) * 64;                                    \
    async16(s0, &L[buf][0][kc0][mb0][0]);                                      \
    async16(s1, &L[buf][0][kc1][mb1][0]);                                      \
    async16(s0 + hs, &L[buf][0][kc0][128 + mb0][0]);                           \
    async16(s1 + hs, &L[buf][0][kc1][128 + mb1][0]);                           \
  } while (0)
#define STG_B(buf, t)                                                          \
  do {                                                                         \
    const u16* s0 = pB0 + (size_t)(t) * 64;                                    \
    const u16* s1 = pB1 + (size_t)(t) * 64;                                    \
    async16(s0, &L[buf][1][kc0][mb0][0]);                                      \
    async16(s1, &L[buf][1][kc1][mb1][0]);                                      \
    async16(s0 + hs, &L[buf][1][kc0][128 + mb0][0]);                           \
    async16(s1 + hs, &L[buf][1][kc1][128 + mb1][0]);                           \
  } while (0)

  // prologue: tiles 0 -> buf0, 1 -> buf1 (16 loads/thread outstanding)
  STG_A(0, 0); STG_B(0, 0);
  STG_A(1, 1); STG_B(1, 1);
  __builtin_amdgcn_s_waitcnt(WAITCNT_VM8);   // tile 0 landed; tile 1 in flight
  __builtin_amdgcn_s_barrier();

  bf16x8 a[4][2], b0[2][2], b1[2][2];
  int I = K >> 7;                            // 2 K-tiles (of 64) per iteration
  for (int i = 0; i < I; ++i) {
    int st = (i + 1 < I);
    // ================= buf0 : K-tile 2i =================
    // PH1
    ld_a4(L[0][0], wm, quad, l15, a);
    ld_b2(L[0][1], wn, quad, l15, b0);
    if (i > 0) STG_B(1, 2 * i + 1);          // buf1 B last read PH6 of prev iter
    __builtin_amdgcn_s_barrier();
    mm16(a, b0, acc, 0, 0);
    __builtin_amdgcn_s_barrier();
    // PH2
    ld_b2(L[0][1], wn + 32, quad, l15, b1);
    __builtin_amdgcn_s_barrier();
    mm16(a, b1, acc, 0, 1);
    __builtin_amdgcn_s_barrier();
    // PH3
    ld_a4(L[0][0], wm + 64, quad, l15, a);
    __builtin_amdgcn_s_barrier();
    mm16(a, b1, acc, 1, 1);
    __builtin_amdgcn_s_barrier();
    // PH4
    if (st) STG_A(0, 2 * i + 2);             // buf0 A last read PH3
    __builtin_amdgcn_s_barrier();
    mm16(a, b0, acc, 1, 0);
    if (st) __builtin_amdgcn_s_waitcnt(WAITCNT_VM4);  // tile 2i+1 fully landed
    else    __builtin_amdgcn_s_waitcnt(WAITCNT_VM0);
    __builtin_amdgcn_s_barrier();
    // ================= buf1 : K-tile 2i+1 =================
    // PH5
    ld_a4(L[1][0], wm, quad, l15, a);
    ld_b2(L[1][1], wn, quad, l15, b0);
    if (st) STG_B(0, 2 * i + 2);             // buf0 B last read PH2
    __builtin_amdgcn_s_barrier();
    mm16(a, b0, acc, 0, 0);
    __builtin_amdgcn_s_barrier();
    // PH6
    ld_b2(L[1][1], wn + 32, quad, l15, b1);
    __builtin_amdgcn_s_barrier();
    mm16(a, b1, acc, 0, 1);
    __builtin_amdgcn_s_barrier();
    // PH7
    ld_a4(L[1][0], wm + 64, quad, l15, a);
    __builtin_amdgcn_s_barrier();
    mm16(a, b1, acc, 1, 1);
    __builtin_amdgcn_s_barrier();
    // PH8
    if (st) STG_A(1, 2 * i + 3);             // buf1 A last read PH7
    __builtin_amdgcn_s_barrier();
    mm16(a, b0, acc, 1, 0);
    if (st) __builtin_amdgcn_s_waitcnt(WAITCNT_VM4);  // tile 2i+2 fully landed
    __builtin_amdgcn_s_barrier();
  }
#undef STG_A
#undef STG_B
}

// ---------------- fused QKV projection GEMM (bx-partitioned, 256^2 tiles) --
__global__ __launch_bounds__(512, 2) void qkv_gemm8(
    const u16* __restrict__ xbf, const u16* __restrict__ ctxbf,
    const u16* __restrict__ WqT, const u16* __restrict__ WkT, const u16* __restrict__ WvT,
    u16* __restrict__ Qb, u16* __restrict__ Kbuf, u16* __restrict__ Vtb, float qscale) {
  int bx = blockIdx.x;
  const u16* A; const u16* Bt; u16* C; int K, mode, m0, n0; float scale;
  if (bx < 256)      { int t = bx;       A = xbf;   Bt = WqT; C = Qb;   K = 1024; mode = 0; scale = qscale; m0 = (t >> 2) * 256; n0 = (t & 3) * 256; }
  else if (bx < 320) { int t = bx - 256; A = ctxbf; Bt = WkT; C = Kbuf; K = 768;  mode = 0; scale = 1.0f;   m0 = (t >> 2) * 256; n0 = (t & 3) * 256; }
  else               { int t = bx - 320; A = ctxbf; Bt = WvT; C = Vtb;  K = 768;  mode = 2; scale = 1.0f;   m0 = (t >> 2) * 256; n0 = (t & 3) * 256; }

  float4v acc[8][4] = {};
  gemm256_core(A, Bt, K, m0, n0, acc);

  int tid = threadIdx.x;
  int w = tid >> 6, lane = tid & 63;
  int l15 = lane & 15, quad = lane >> 4;
  int wm = (w >> 2) * 128, wn = (w & 3) * 64;

  if (mode == 0) {
#pragma unroll
    for (int mi = 0; mi < 8; mi++) {
      int rowb = m0 + wm + mi * 16 + quad * 4;
#pragma unroll
      for (int ni = 0; ni < 4; ni++) {
        int col = n0 + wn + ni * 16 + l15;
#pragma unroll
        for (int r = 0; r < 4; r++)
          C[(size_t)(rowb + r) * 1024 + col] = f2bf(acc[mi][ni][r] * scale);
      }
    }
  } else {
#pragma unroll
    for (int mi = 0; mi < 8; mi++) {
      int rowb = m0 + wm + mi * 16 + quad * 4;
#pragma unroll
      for (int ni = 0; ni < 4; ni++) {
        int col = n0 + wn + ni * 16 + l15;
        int hh = col >> 6, dd = col & 63;
#pragma unroll
        for (int r = 0; r < 4; r++) {
          int rr = rowb + r;
          int b = rr >> 10, skv = rr & 1023;
          _Float16 hv = (_Float16)acc[mi][ni][r];
          C[((((size_t)b * 16 + hh) * 64 + dd) << 10) + skv] = __builtin_bit_cast(u16, hv);
        }
      }
    }
  }
}

// ---------------- output projection: out = attn*WoT^T + bo (fp32, 256^2) ---
__global__ __launch_bounds__(512, 2) void gemm_bt8(
    const u16* __restrict__ A, const u16* __restrict__ Bt,
    float* __restrict__ C, const float* __restrict__ bias) {
  int bx = blockIdx.x;
  int m0 = (bx >> 2) * 256, n0 = (bx & 3) * 256;

  float4v acc[8][4] = {};
  gemm256_core(A, Bt, 1024, m0, n0, acc);

  int tid = threadIdx.x;
  int w = tid >> 6, lane = tid & 63;
  int l15 = lane & 15, quad = lane >> 4;
  int wm = (w >> 2) * 128, wn = (w & 3) * 64;

#pragma unroll
  for (int mi = 0; mi < 8; mi++) {
    int rowb = m0 + wm + mi * 16 + quad * 4;
#pragma unroll
    for (int ni = 0; ni < 4; ni++) {
      int col = n0 + wn + ni * 16 + l15;
      float bv = bias[col];
#pragma unroll
      for (int r = 0; r < 4; r++)
        C[(size_t)(rowb + r) * 1024 + col] = acc[mi][ni][r] + bv;
    }
  }
}

// ---------------- attention v9: per (b,h), O = softmax(Q K^T) V -------------
// grid (SQ/256, B*H), block 512 (8 waves, 32 q each), launch_bounds(512,4).
// KVBLK=128: 8 iterations (was 16). LDS 64KB: lK[2][128kv][64d] bf16 swizzled
// (3-bit XOR on 8-chunk rows), lV[2][64d][128kv] f16 swizzled (4-bit XOR on
// 16-chunk rows). 2 K-chunks + 2 V-chunks staged per thread per iter.
// Max-free softmax, S^T trick, in-register P, K=16 f16 PV (R10 structure).
__global__ __launch_bounds__(512, 4) void attn_kernel(
    const u16* __restrict__ Q, const u16* __restrict__ Kb,
    const u16* __restrict__ Vt, u16* __restrict__ Oout) {
  __shared__ __align__(16) u16 lK[2][8192];   // 128kv x 64d bf16, XOR-swizzled
  __shared__ __align__(16) u16 lV[2][8192];   // 64d x 128kv f16, XOR-swizzled
  int tid = threadIdx.x, w = tid >> 6, lane = tid & 63;
  int l15 = lane & 15, quad = lane >> 4;
  int bh = blockIdx.y, b = bh >> 4, h = bh & 15;
  int q0 = blockIdx.x * 256 + w * 32;

  const u16* Qbase = Q + ((size_t)(b * 4096 + q0)) * 1024 + h * 64;
  const u16* Kbase = Kb + ((size_t)b << 20) + h * 64;
  const u16* Vbase = Vt + ((size_t)bh << 16);

  // Q B-fragments, resident whole kernel: [qt][c], lane: q=qt*16+l15, d=c*32+quad*8..+7
  bf16x8 qf[2][2];
#pragma unroll
  for (int qt = 0; qt < 2; qt++)
#pragma unroll
    for (int c = 0; c < 2; c++)
      qf[qt][c] = *(const bf16x8*)(Qbase + (size_t)(qt * 16 + l15) * 1024 + c * 32 + quad * 8);

  // K staging: slot s (s0=tid, s1=tid+512): kv-row r=s>>3, chunk (s&7)^(r&7)
  int kr0 = tid >> 3, kx0 = ((tid & 7) ^ (kr0 & 7)) * 8;
  const u16* ks0 = Kbase + (size_t)kr0 * 1024 + kx0;
  const u16* ks1 = ks0 + (size_t)64 * 1024;          // row +64, same XOR (64%8==0)
  // V staging: slot s: d-row d=s>>4, chunk c=s&15 -> global chunk c^(d&15)
  int vd0 = tid >> 4, vc0 = ((tid & 15) ^ (vd0 & 15)) * 8;
  const u16* vs0 = Vbase + (size_t)vd0 * 1024 + vc0;
  const u16* vs1 = vs0 + (size_t)32 * 1024;          // row +32, same XOR (32%16==0)
  int kdo0 = w * 512, kdo1 = 4096 + w * 512;         // u16 offsets within a buffer

  // prologue: stage iter 0 into buffer 0
  async16(ks0, &lK[0][kdo0]); async16(ks1, &lK[0][kdo1]);
  async16(vs0, &lV[0][kdo0]); async16(vs1, &lV[0][kdo1]);
  ks0 += 131072; ks1 += 131072;    // +128 kv rows
  vs0 += 128; vs1 += 128;          // +128 along skv

  float4v o[2][4] = {};     // [qt][dt] O^T accumulators (C-layout)
  float4v osum[2] = {};     // row sums via ones-MFMA (every lane gets its q's sum)
  const half4 ones = {(_Float16)1.0f, (_Float16)1.0f, (_Float16)1.0f, (_Float16)1.0f};

  // hoisted LDS read base pieces (bytes, within one buffer)
  int lb = l15 & 7;
  int xk0 = ((0 + quad) ^ lb) * 16 + l15 * 128;   // c=0 K-frag offset (sub-invariant)
  int xk1 = ((4 + quad) ^ lb) * 16 + l15 * 128;   // c=1
  int qh = quad >> 1, qo = (quad & 1) * 8;
  int vrow = l15 * 256 + qo;                       // V-frag: + ((sub*2+qh)^l15)*16

  for (int it = 0; it < 8; ++it) {
    const char* bK = (const char*)lK + (it & 1) * 16384;
    const char* bV = (const char*)lV + (it & 1) * 16384;
    __syncthreads();   // drains loads issued LAST iter + guards buffers
    if (it < 7) {
      int nb = (it + 1) & 1;
      async16(ks0, &lK[nb][kdo0]); async16(ks1, &lK[nb][kdo1]);
      async16(vs0, &lV[nb][kdo0]); async16(vs1, &lV[nb][kdo1]);
      ks0 += 131072; ks1 += 131072;
      vs0 += 128; vs1 += 128;
    }
#pragma unroll
    for (int ss = 0; ss < 8; ss++) {
      int sub = (ss + w) & 7;            // per-wave rotation: anti-lockstep
      int sb = sub * 2048;               // byte offset: sub*16 kv-rows x 128B
      // S^T tile: rows kv=sub*16+quad*4+r, cols q=qt*16+l15
      float4v sv[2] = {{0.f, 0.f, 0.f, 0.f}, {0.f, 0.f, 0.f, 0.f}};
      __builtin_amdgcn_s_setprio(1);
#pragma unroll
      for (int c = 0; c < 2; c++) {
        bf16x8 kf = *(const bf16x8*)(bK + sb + (c ? xk1 : xk0));
#pragma unroll
        for (int qt = 0; qt < 2; qt++)
          sv[qt] = __builtin_amdgcn_mfma_f32_16x16x32_bf16(kf, qf[qt][c], sv[qt], 0, 0, 0);
      }
      __builtin_amdgcn_s_setprio(0);
      // P = exp2(S') (log2e folded into Q scale); pack f16; sums via ones-MFMA
      half4 pf[2];
#pragma unroll
      for (int qt = 0; qt < 2; qt++) {
        float e0 = exp2f(sv[qt][0]), e1 = exp2f(sv[qt][1]);
        float e2 = exp2f(sv[qt][2]), e3 = exp2f(sv[qt][3]);
        half2v p01 = __builtin_bit_cast(half2v, __builtin_amdgcn_cvt_pkrtz(e0, e1));
        half2v p23 = __builtin_bit_cast(half2v, __builtin_amdgcn_cvt_pkrtz(e2, e3));
        pf[qt] = __builtin_shufflevector(p01, p23, 0, 1, 2, 3);
        osum[qt] = __builtin_amdgcn_mfma_f32_16x16x16f16(ones, pf[qt], osum[qt], 0, 0, 0);
      }
      // O^T += V^T * P^T  (K=16 MFMA; P fragment straight from registers)
      int vbs = vrow + (((sub * 2 + qh) ^ l15) * 16);
      __builtin_amdgcn_s_setprio(1);
#pragma unroll
      for (int dt = 0; dt < 4; dt++) {
        half4 vf = *(const half4*)(bV + dt * 4096 + vbs);
#pragma unroll
        for (int qt = 0; qt < 2; qt++)
          o[qt][dt] = __builtin_amdgcn_mfma_f32_16x16x16f16(vf, pf[qt], o[qt][dt], 0, 0, 0);
      }
      __builtin_amdgcn_s_setprio(0);
    }
  }

#pragma unroll
  for (int qt = 0; qt < 2; qt++) {
    float inv = 1.0f / osum[qt][0];   // all rows of the ones-product are the q-col sum
    u16* Ob = Oout + ((size_t)(b * 4096 + q0 + qt * 16 + l15)) * 1024 + h * 64 + quad * 4;
#pragma unroll
    for (int dt = 0; dt < 4; dt++) {
      ushort4 pk;
      pk.x = f2bf(o[qt][dt][0] * inv);
      pk.y = f2bf(o[qt][dt][1] * inv);
      pk.z = f2bf(o[qt][dt][2] * inv);
      pk.w = f2bf(o[qt][dt][3] * inv);
      *(ushort4*)(Ob + dt * 16) = pk;
    }
  }
}

// ---------------------------------------------------------------------------
extern "C" void kernel_launch(void* const* d_in, const int* in_sizes, int n_in,
                              void* d_out, int out_size, void* d_ws, size_t ws_size,
                              hipStream_t stream) {
  const float* x   = (const float*)d_in[0];
  const float* ctx = (const float*)d_in[1];
  const float* Wq  = (const float*)d_in[2];
  const float* Wk  = (const float*)d_in[3];
  const float* Wv  = (const float*)d_in[4];
  const float* Wo  = (const float*)d_in[5];
  const float* bo  = (const float*)d_in[6];
  float* out = (float*)d_out;

  u16* ws    = (u16*)d_ws;
  u16* xbf   = ws;                  // 16777216 elems (reused as attn_out)
  u16* ctxbf = xbf + 16777216;      // 3145728
  u16* WqT   = ctxbf + 3145728;     // 1048576
  u16* WkT   = WqT + 1048576;       // 786432
  u16* WvT   = WkT + 786432;        // 786432
  u16* WoT   = WvT + 786432;        // 1048576
  u16* Qb    = WoT + 1048576;       // 16777216
  u16* Kbuf  = Qb + 16777216;       // 4194304
  u16* Vtb   = Kbuf + 4194304;      // 4194304 (f16)  -> total ~93 MB
  if (ws_size < (size_t)48758784 * 2) return;  // workspace too small: clean fail

  cvt_kernel<<<19456, 256, 0, stream>>>(x, xbf, ctx, ctxbf);
  twt_kernel<<<dim3(32, 32, 4), dim3(32, 8), 0, stream>>>(Wq, Wk, Wv, Wo, WqT, WkT, WvT, WoT);
  // 256 Q-blocks + 64 K-blocks + 64 V-blocks, 512 threads, 8-phase schedule
  qkv_gemm8<<<dim3(384), dim3(512), 0, stream>>>(xbf, ctxbf, WqT, WkT, WvT,
                                                 Qb, Kbuf, Vtb, 0.18033688011112042f);
  // attention -> attn_out (bf16, [b, sq, h*64+d]), reusing xbf
  attn_kernel<<<dim3(16, 64), dim3(512), 0, stream>>>(Qb, Kbuf, Vtb, xbf);
  // out = attn_out*Wo + bo (fp32), 64x4 tiles of 256^2
  gemm_bt8<<<dim3(256), dim3(512), 0, stream>>>(xbf, WoT, out, bo);
}

// Round 10
// 347.349 us; speedup vs baseline: 1.4933x; 1.0890x over previous
//
#include <hip/hip_runtime.h>

// ---------------------------------------------------------------------------
// CrossAttentionMM on MI355X (gfx950), bf16 MFMA pipeline.
// B=4, SQ=4096, SKV=1024, QDIM=1024, CDIM=768, H=16, D=64, INNER=1024.
// R15: GEMM staging coalesced. Old STG was lane->row (64 lanes x 16B at 2KB
// stride = 64 txns/load). New: row-major [256][64] LDS with 3-bit XOR chunk
// swizzle (attn's proven pattern): wave stages 4x 1KB windows (8 rows x 64k),
// lane reads row w*32+j*8+(lane>>3), global chunk (lane&7)^(lane>>3) -> 16
// txns/load (4x fewer). Fragment ds_reads XOR the same key -> all 32 banks
// (min-conflict, same as before). Schedule/vmcnt/phases/epilogue IDENTICAL.
// Totals say the 2 GEMMs eat ~240us (each just under attn's 116us top-5
// cutoff) at ~300-410 TF vs the m201 template's 1563 TF same-config.
// attn v9 (R14, 115.9us) / cvt / twt unchanged.
// ---------------------------------------------------------------------------

typedef unsigned short u16;
typedef unsigned int u32;
typedef __bf16 bf16x8 __attribute__((ext_vector_type(8)));
typedef float float4v __attribute__((ext_vector_type(4)));
typedef _Float16 half4 __attribute__((ext_vector_type(4)));
typedef _Float16 half2v __attribute__((ext_vector_type(2)));
typedef __attribute__((address_space(1))) void as1_void;
typedef __attribute__((address_space(3))) void as3_void;

__device__ __forceinline__ u16 f2bf(float f) {
  unsigned u = __float_as_uint(f);
  u += 0x7FFF + ((u >> 16) & 1);   // RTNE
  return (u16)(u >> 16);
}

// async global->LDS, 16B per lane. LDS dest = wave-uniform base + lane*16.
__device__ __forceinline__ void async16(const u16* g, u16* l) {
  __builtin_amdgcn_global_load_lds((as1_void*)(void*)g, (as3_void*)l, 16, 0, 0);
}

// gfx9 waitcnt imm: vmcnt[3:0]=imm[3:0], exp=imm[6:4], lgkm=imm[11:8], vmcnt[5:4]=imm[15:14]
#define WAITCNT_VM8 0xF78   // vmcnt(8), lgkm/exp no-wait
#define WAITCNT_VM4 0xF74   // vmcnt(4)
#define WAITCNT_VM0 0xF70   // vmcnt(0)

// ---------------- fp32 -> bf16 cast: x then ctx, one launch ----------------
__global__ void cvt_kernel(const float* __restrict__ x, u16* __restrict__ xbf,
                           const float* __restrict__ ctx, u16* __restrict__ ctxbf) {
  int i = blockIdx.x * 256 + threadIdx.x;
  const float* in; u16* out; int j;
  if (i < 4194304) { in = x; out = xbf; j = i; }
  else if (i < 4980736) { in = ctx; out = ctxbf; j = i - 4194304; }
  else return;
  float4 v = ((const float4*)in)[j];
  ushort4 o;
  o.x = f2bf(v.x); o.y = f2bf(v.y); o.z = f2bf(v.z); o.w = f2bf(v.w);
  ((ushort4*)out)[j] = o;
}

// ---------------- all 4 weights: W[K,N] fp32 -> Wt[N,K] bf16, one launch ----
__global__ void twt_kernel(const float* __restrict__ Wq, const float* __restrict__ Wk,
                           const float* __restrict__ Wv, const float* __restrict__ Wo,
                           u16* __restrict__ WqT, u16* __restrict__ WkT,
                           u16* __restrict__ WvT, u16* __restrict__ WoT) {
  __shared__ u16 t[32][33];
  int z = blockIdx.z;
  const float* W = z == 0 ? Wq : z == 1 ? Wk : z == 2 ? Wv : Wo;
  u16* Wt = z == 0 ? WqT : z == 1 ? WkT : z == 2 ? WvT : WoT;
  int Kd = (z == 1 || z == 2) ? 768 : 1024;
  int k0 = blockIdx.y * 32;
  if (k0 >= Kd) return;
  int tx = threadIdx.x, ty = threadIdx.y;
  int n0 = blockIdx.x * 32;
#pragma unroll
  for (int i = 0; i < 4; i++)
    t[ty + i * 8][tx] = f2bf(W[(size_t)(k0 + ty + i * 8) * 1024 + n0 + tx]);
  __syncthreads();
#pragma unroll
  for (int i = 0; i < 4; i++)
    Wt[(size_t)(n0 + ty + i * 8) * Kd + k0 + tx] = t[tx][ty + i * 8];
}

// ---------------------------------------------------------------------------
// 256x256 / BK=64 / 8-wave 8-phase GEMM core (C = A * Bt^T), bf16 inputs.
// LDS: [buf][A/B][row(256)][k(64)] bf16, 3-bit XOR chunk swizzle per row.
// ---------------------------------------------------------------------------

__device__ __forceinline__ void ld_a4(const u16* Lp, int rbase, int quad,
                                      int l15, bf16x8 a[4][2]) {
  int lb = l15 & 7;
  const char* base = (const char*)Lp;
#pragma unroll
  for (int mi = 0; mi < 4; mi++)
#pragma unroll
    for (int ks = 0; ks < 2; ks++)
      a[mi][ks] = *(const bf16x8*)(base + (rbase + mi * 16 + l15) * 128 +
                                   (((ks * 4 + quad) ^ lb) << 4));
}

__device__ __forceinline__ void ld_b2(const u16* Lp, int rbase, int quad,
                                      int l15, bf16x8 b[2][2]) {
  int lb = l15 & 7;
  const char* base = (const char*)Lp;
#pragma unroll
  for (int ni = 0; ni < 2; ni++)
#pragma unroll
    for (int ks = 0; ks < 2; ks++)
      b[ni][ks] = *(const bf16x8*)(base + (rbase + ni * 16 + l15) * 128 +
                                   (((ks * 4 + quad) ^ lb) << 4));
}

__device__ __forceinline__ void mm16(bf16x8 a[4][2], bf16x8 b[2][2],
                                     float4v acc[8][4], int mh, int nh) {
  __builtin_amdgcn_s_setprio(1);
#pragma unroll
  for (int mi = 0; mi < 4; mi++)
#pragma unroll
    for (int ni = 0; ni < 2; ni++)
#pragma unroll
      for (int ks = 0; ks < 2; ks++)
        acc[mh * 4 + mi][nh * 2 + ni] = __builtin_amdgcn_mfma_f32_16x16x32_bf16(
            a[mi][ks], b[ni][ks], acc[mh * 4 + mi][nh * 2 + ni], 0, 0, 0);
  __builtin_amdgcn_s_setprio(0);
}

__device__ __forceinline__ void gemm256_core(const u16* __restrict__ A,
                                             const u16* __restrict__ Bt, int K,
                                             int m0, int n0, float4v acc[8][4]) {
  __shared__ __align__(16) u16 L[2][2][256][64];   // 128 KiB
  int tid = threadIdx.x;
  int w = tid >> 6, lane = tid & 63;
  int l15 = lane & 15, quad = lane >> 4;
  int wm = (w >> 2) * 128, wn = (w & 3) * 64;

  // staging: wave w owns rows [w*32, w*32+32) as 4 windows of 8 rows x 64 k
  // (1KB each, coalesced). lane: local row lr=lane>>3, LDS slot sl=lane&7,
  // global chunk sl^lr (3-bit XOR; (row&7)==lr since windows are 8-aligned).
  int lr = lane >> 3, sl = lane & 7;
  const u16* pA = A + (size_t)(m0 + (w << 5) + lr) * K + ((sl ^ lr) << 3);
  const u16* pB = Bt + (size_t)(n0 + (w << 5) + lr) * K + ((sl ^ lr) << 3);
  size_t r8 = (size_t)K << 3;      // +8 rows (u16 elems)
  int dofs = (w << 11) + lane * 8; // u16 offset of window 0 dest within matrix

#define STG_A(buf, t)                                                          \
  do {                                                                         \
    const u16* s = pA + (size_t)(t) * 64;                                      \
    u16* d = &L[buf][0][0][0] + dofs;                                          \
    async16(s, d);                                                             \
    async16(s + r8, d + 512);                                                  \
    async16(s + 2 * r8, d + 1024);                                             \
    async16(s + 3 * r8, d + 1536);                                             \
  } while (0)
#define STG_B(buf, t)                                                          \
  do {                                                                         \
    const u16* s = pB + (size_t)(t) * 64;                                      \
    u16* d = &L[buf][1][0][0] + dofs;                                          \
    async16(s, d);                                                             \
    async16(s + r8, d + 512);                                                  \
    async16(s + 2 * r8, d + 1024);                                             \
    async16(s + 3 * r8, d + 1536);                                             \
  } while (0)

  // prologue: tiles 0 -> buf0, 1 -> buf1 (16 loads/thread outstanding)
  STG_A(0, 0); STG_B(0, 0);
  STG_A(1, 1); STG_B(1, 1);
  __builtin_amdgcn_s_waitcnt(WAITCNT_VM8);   // tile 0 landed; tile 1 in flight
  __builtin_amdgcn_s_barrier();

  bf16x8 a[4][2], b0[2][2], b1[2][2];
  int I = K >> 7;                            // 2 K-tiles (of 64) per iteration
  for (int i = 0; i < I; ++i) {
    int st = (i + 1 < I);
    // ================= buf0 : K-tile 2i =================
    // PH1
    ld_a4(&L[0][0][0][0], wm, quad, l15, a);
    ld_b2(&L[0][1][0][0], wn, quad, l15, b0);
    if (i > 0) STG_B(1, 2 * i + 1);          // buf1 B last read PH6 of prev iter
    __builtin_amdgcn_s_barrier();
    mm16(a, b0, acc, 0, 0);
    __builtin_amdgcn_s_barrier();
    // PH2
    ld_b2(&L[0][1][0][0], wn + 32, quad, l15, b1);
    __builtin_amdgcn_s_barrier();
    mm16(a, b1, acc, 0, 1);
    __builtin_amdgcn_s_barrier();
    // PH3
    ld_a4(&L[0][0][0][0], wm + 64, quad, l15, a);
    __builtin_amdgcn_s_barrier();
    mm16(a, b1, acc, 1, 1);
    __builtin_amdgcn_s_barrier();
    // PH4
    if (st) STG_A(0, 2 * i + 2);             // buf0 A last read PH3
    __builtin_amdgcn_s_barrier();
    mm16(a, b0, acc, 1, 0);
    if (st) __builtin_amdgcn_s_waitcnt(WAITCNT_VM4);  // tile 2i+1 fully landed
    else    __builtin_amdgcn_s_waitcnt(WAITCNT_VM0);
    __builtin_amdgcn_s_barrier();
    // ================= buf1 : K-tile 2i+1 =================
    // PH5
    ld_a4(&L[1][0][0][0], wm, quad, l15, a);
    ld_b2(&L[1][1][0][0], wn, quad, l15, b0);
    if (st) STG_B(0, 2 * i + 2);             // buf0 B last read PH2
    __builtin_amdgcn_s_barrier();
    mm16(a, b0, acc, 0, 0);
    __builtin_amdgcn_s_barrier();
    // PH6
    ld_b2(&L[1][1][0][0], wn + 32, quad, l15, b1);
    __builtin_amdgcn_s_barrier();
    mm16(a, b1, acc, 0, 1);
    __builtin_amdgcn_s_barrier();
    // PH7
    ld_a4(&L[1][0][0][0], wm + 64, quad, l15, a);
    __builtin_amdgcn_s_barrier();
    mm16(a, b1, acc, 1, 1);
    __builtin_amdgcn_s_barrier();
    // PH8
    if (st) STG_A(1, 2 * i + 3);             // buf1 A last read PH7
    __builtin_amdgcn_s_barrier();
    mm16(a, b0, acc, 1, 0);
    if (st) __builtin_amdgcn_s_waitcnt(WAITCNT_VM4);  // tile 2i+2 fully landed
    __builtin_amdgcn_s_barrier();
  }
#undef STG_A
#undef STG_B
}

// ---------------- fused QKV projection GEMM (bx-partitioned, 256^2 tiles) --
__global__ __launch_bounds__(512, 2) void qkv_gemm8(
    const u16* __restrict__ xbf, const u16* __restrict__ ctxbf,
    const u16* __restrict__ WqT, const u16* __restrict__ WkT, const u16* __restrict__ WvT,
    u16* __restrict__ Qb, u16* __restrict__ Kbuf, u16* __restrict__ Vtb, float qscale) {
  int bx = blockIdx.x;
  const u16* A; const u16* Bt; u16* C; int K, mode, m0, n0; float scale;
  if (bx < 256)      { int t = bx;       A = xbf;   Bt = WqT; C = Qb;   K = 1024; mode = 0; scale = qscale; m0 = (t >> 2) * 256; n0 = (t & 3) * 256; }
  else if (bx < 320) { int t = bx - 256; A = ctxbf; Bt = WkT; C = Kbuf; K = 768;  mode = 0; scale = 1.0f;   m0 = (t >> 2) * 256; n0 = (t & 3) * 256; }
  else               { int t = bx - 320; A = ctxbf; Bt = WvT; C = Vtb;  K = 768;  mode = 2; scale = 1.0f;   m0 = (t >> 2) * 256; n0 = (t & 3) * 256; }

  float4v acc[8][4] = {};
  gemm256_core(A, Bt, K, m0, n0, acc);

  int tid = threadIdx.x;
  int w = tid >> 6, lane = tid & 63;
  int l15 = lane & 15, quad = lane >> 4;
  int wm = (w >> 2) * 128, wn = (w & 3) * 64;

  if (mode == 0) {
#pragma unroll
    for (int mi = 0; mi < 8; mi++) {
      int rowb = m0 + wm + mi * 16 + quad * 4;
#pragma unroll
      for (int ni = 0; ni < 4; ni++) {
        int col = n0 + wn + ni * 16 + l15;
#pragma unroll
        for (int r = 0; r < 4; r++)
          C[(size_t)(rowb + r) * 1024 + col] = f2bf(acc[mi][ni][r] * scale);
      }
    }
  } else {
#pragma unroll
    for (int mi = 0; mi < 8; mi++) {
      int rowb = m0 + wm + mi * 16 + quad * 4;
#pragma unroll
      for (int ni = 0; ni < 4; ni++) {
        int col = n0 + wn + ni * 16 + l15;
        int hh = col >> 6, dd = col & 63;
#pragma unroll
        for (int r = 0; r < 4; r++) {
          int rr = rowb + r;
          int b = rr >> 10, skv = rr & 1023;
          _Float16 hv = (_Float16)acc[mi][ni][r];
          C[((((size_t)b * 16 + hh) * 64 + dd) << 10) + skv] = __builtin_bit_cast(u16, hv);
        }
      }
    }
  }
}

// ---------------- output projection: out = attn*WoT^T + bo (fp32, 256^2) ---
__global__ __launch_bounds__(512, 2) void gemm_bt8(
    const u16* __restrict__ A, const u16* __restrict__ Bt,
    float* __restrict__ C, const float* __restrict__ bias) {
  int bx = blockIdx.x;
  int m0 = (bx >> 2) * 256, n0 = (bx & 3) * 256;

  float4v acc[8][4] = {};
  gemm256_core(A, Bt, 1024, m0, n0, acc);

  int tid = threadIdx.x;
  int w = tid >> 6, lane = tid & 63;
  int l15 = lane & 15, quad = lane >> 4;
  int wm = (w >> 2) * 128, wn = (w & 3) * 64;

#pragma unroll
  for (int mi = 0; mi < 8; mi++) {
    int rowb = m0 + wm + mi * 16 + quad * 4;
#pragma unroll
    for (int ni = 0; ni < 4; ni++) {
      int col = n0 + wn + ni * 16 + l15;
      float bv = bias[col];
#pragma unroll
      for (int r = 0; r < 4; r++)
        C[(size_t)(rowb + r) * 1024 + col] = acc[mi][ni][r] + bv;
    }
  }
}

// ---------------- attention v9: per (b,h), O = softmax(Q K^T) V -------------
// grid (SQ/256, B*H), block 512 (8 waves, 32 q each), launch_bounds(512,4).
// KVBLK=128: 8 iterations. LDS 64KB double-buffered, XOR-swizzled.
__global__ __launch_bounds__(512, 4) void attn_kernel(
    const u16* __restrict__ Q, const u16* __restrict__ Kb,
    const u16* __restrict__ Vt, u16* __restrict__ Oout) {
  __shared__ __align__(16) u16 lK[2][8192];   // 128kv x 64d bf16, XOR-swizzled
  __shared__ __align__(16) u16 lV[2][8192];   // 64d x 128kv f16, XOR-swizzled
  int tid = threadIdx.x, w = tid >> 6, lane = tid & 63;
  int l15 = lane & 15, quad = lane >> 4;
  int bh = blockIdx.y, b = bh >> 4, h = bh & 15;
  int q0 = blockIdx.x * 256 + w * 32;

  const u16* Qbase = Q + ((size_t)(b * 4096 + q0)) * 1024 + h * 64;
  const u16* Kbase = Kb + ((size_t)b << 20) + h * 64;
  const u16* Vbase = Vt + ((size_t)bh << 16);

  bf16x8 qf[2][2];
#pragma unroll
  for (int qt = 0; qt < 2; qt++)
#pragma unroll
    for (int c = 0; c < 2; c++)
      qf[qt][c] = *(const bf16x8*)(Qbase + (size_t)(qt * 16 + l15) * 1024 + c * 32 + quad * 8);

  int kr0 = tid >> 3, kx0 = ((tid & 7) ^ (kr0 & 7)) * 8;
  const u16* ks0 = Kbase + (size_t)kr0 * 1024 + kx0;
  const u16* ks1 = ks0 + (size_t)64 * 1024;
  int vd0 = tid >> 4, vc0 = ((tid & 15) ^ (vd0 & 15)) * 8;
  const u16* vs0 = Vbase + (size_t)vd0 * 1024 + vc0;
  const u16* vs1 = vs0 + (size_t)32 * 1024;
  int kdo0 = w * 512, kdo1 = 4096 + w * 512;

  async16(ks0, &lK[0][kdo0]); async16(ks1, &lK[0][kdo1]);
  async16(vs0, &lV[0][kdo0]); async16(vs1, &lV[0][kdo1]);
  ks0 += 131072; ks1 += 131072;
  vs0 += 128; vs1 += 128;

  float4v o[2][4] = {};
  float4v osum[2] = {};
  const half4 ones = {(_Float16)1.0f, (_Float16)1.0f, (_Float16)1.0f, (_Float16)1.0f};

  int lb = l15 & 7;
  int xk0 = ((0 + quad) ^ lb) * 16 + l15 * 128;
  int xk1 = ((4 + quad) ^ lb) * 16 + l15 * 128;
  int qh = quad >> 1, qo = (quad & 1) * 8;
  int vrow = l15 * 256 + qo;

  for (int it = 0; it < 8; ++it) {
    const char* bK = (const char*)lK + (it & 1) * 16384;
    const char* bV = (const char*)lV + (it & 1) * 16384;
    __syncthreads();
    if (it < 7) {
      int nb = (it + 1) & 1;
      async16(ks0, &lK[nb][kdo0]); async16(ks1, &lK[nb][kdo1]);
      async16(vs0, &lV[nb][kdo0]); async16(vs1, &lV[nb][kdo1]);
      ks0 += 131072; ks1 += 131072;
      vs0 += 128; vs1 += 128;
    }
#pragma unroll
    for (int ss = 0; ss < 8; ss++) {
      int sub = (ss + w) & 7;
      int sb = sub * 2048;
      float4v sv[2] = {{0.f, 0.f, 0.f, 0.f}, {0.f, 0.f, 0.f, 0.f}};
      __builtin_amdgcn_s_setprio(1);
#pragma unroll
      for (int c = 0; c < 2; c++) {
        bf16x8 kf = *(const bf16x8*)(bK + sb + (c ? xk1 : xk0));
#pragma unroll
        for (int qt = 0; qt < 2; qt++)
          sv[qt] = __builtin_amdgcn_mfma_f32_16x16x32_bf16(kf, qf[qt][c], sv[qt], 0, 0, 0);
      }
      __builtin_amdgcn_s_setprio(0);
      half4 pf[2];
#pragma unroll
      for (int qt = 0; qt < 2; qt++) {
        float e0 = exp2f(sv[qt][0]), e1 = exp2f(sv[qt][1]);
        float e2 = exp2f(sv[qt][2]), e3 = exp2f(sv[qt][3]);
        half2v p01 = __builtin_bit_cast(half2v, __builtin_amdgcn_cvt_pkrtz(e0, e1));
        half2v p23 = __builtin_bit_cast(half2v, __builtin_amdgcn_cvt_pkrtz(e2, e3));
        pf[qt] = __builtin_shufflevector(p01, p23, 0, 1, 2, 3);
        osum[qt] = __builtin_amdgcn_mfma_f32_16x16x16f16(ones, pf[qt], osum[qt], 0, 0, 0);
      }
      int vbs = vrow + (((sub * 2 + qh) ^ l15) * 16);
      __builtin_amdgcn_s_setprio(1);
#pragma unroll
      for (int dt = 0; dt < 4; dt++) {
        half4 vf = *(const half4*)(bV + dt * 4096 + vbs);
#pragma unroll
        for (int qt = 0; qt < 2; qt++)
          o[qt][dt] = __builtin_amdgcn_mfma_f32_16x16x16f16(vf, pf[qt], o[qt][dt], 0, 0, 0);
      }
      __builtin_amdgcn_s_setprio(0);
    }
  }

#pragma unroll
  for (int qt = 0; qt < 2; qt++) {
    float inv = 1.0f / osum[qt][0];
    u16* Ob = Oout + ((size_t)(b * 4096 + q0 + qt * 16 + l15)) * 1024 + h * 64 + quad * 4;
#pragma unroll
    for (int dt = 0; dt < 4; dt++) {
      ushort4 pk;
      pk.x = f2bf(o[qt][dt][0] * inv);
      pk.y = f2bf(o[qt][dt][1] * inv);
      pk.z = f2bf(o[qt][dt][2] * inv);
      pk.w = f2bf(o[qt][dt][3] * inv);
      *(ushort4*)(Ob + dt * 16) = pk;
    }
  }
}

// ---------------------------------------------------------------------------
extern "C" void kernel_launch(void* const* d_in, const int* in_sizes, int n_in,
                              void* d_out, int out_size, void* d_ws, size_t ws_size,
                              hipStream_t stream) {
  const float* x   = (const float*)d_in[0];
  const float* ctx = (const float*)d_in[1];
  const float* Wq  = (const float*)d_in[2];
  const float* Wk  = (const float*)d_in[3];
  const float* Wv  = (const float*)d_in[4];
  const float* Wo  = (const float*)d_in[5];
  const float* bo  = (const float*)d_in[6];
  float* out = (float*)d_out;

  u16* ws    = (u16*)d_ws;
  u16* xbf   = ws;                  // 16777216 elems (reused as attn_out)
  u16* ctxbf = xbf + 16777216;      // 3145728
  u16* WqT   = ctxbf + 3145728;     // 1048576
  u16* WkT   = WqT + 1048576;       // 786432
  u16* WvT   = WkT + 786432;        // 786432
  u16* WoT   = WvT + 786432;        // 1048576
  u16* Qb    = WoT + 1048576;       // 16777216
  u16* Kbuf  = Qb + 16777216;       // 4194304
  u16* Vtb   = Kbuf + 4194304;      // 4194304 (f16)  -> total ~93 MB
  if (ws_size < (size_t)48758784 * 2) return;  // workspace too small: clean fail

  cvt_kernel<<<19456, 256, 0, stream>>>(x, xbf, ctx, ctxbf);
  twt_kernel<<<dim3(32, 32, 4), dim3(32, 8), 0, stream>>>(Wq, Wk, Wv, Wo, WqT, WkT, WvT, WoT);
  // 256 Q-blocks + 64 K-blocks + 64 V-blocks, 512 threads, 8-phase schedule
  qkv_gemm8<<<dim3(384), dim3(512), 0, stream>>>(xbf, ctxbf, WqT, WkT, WvT,
                                                 Qb, Kbuf, Vtb, 0.18033688011112042f);
  // attention -> attn_out (bf16, [b, sq, h*64+d]), reusing xbf
  attn_kernel<<<dim3(16, 64), dim3(512), 0, stream>>>(Qb, Kbuf, Vtb, xbf);
  // out = attn_out*Wo + bo (fp32), 64x4 tiles of 256^2
  gemm_bt8<<<dim3(256), dim3(512), 0, stream>>>(xbf, WoT, out, bo);
}

// Round 11
// 342.000 us; speedup vs baseline: 1.5166x; 1.0156x over previous
//
#include <hip/hip_runtime.h>

// ---------------------------------------------------------------------------
// CrossAttentionMM on MI355X (gfx950), bf16 MFMA pipeline.
// B=4, SQ=4096, SKV=1024, QDIM=1024, CDIM=768, H=16, D=64, INNER=1024.
// R16: bijective XCD-aware block swizzle (T1) on both GEMM grids.
// Mechanism: 4 consecutive tiles share one 512KB A-panel; default round-robin
// scatters them over 8 XCD L2s -> each panel HBM-fetched 4x. Chunked mapping
// t=(bx&7)*(nwg/8)+bx>>3 gives each XCD a contiguous tile range -> panel
// reuse within one L2. 384%8==0, 256%8==0 -> simple swizzle is bijective.
// R15 (coalesced swizzled staging, -31us) / attn v9 / cvt / twt unchanged.
// ---------------------------------------------------------------------------

typedef unsigned short u16;
typedef unsigned int u32;
typedef __bf16 bf16x8 __attribute__((ext_vector_type(8)));
typedef float float4v __attribute__((ext_vector_type(4)));
typedef _Float16 half4 __attribute__((ext_vector_type(4)));
typedef _Float16 half2v __attribute__((ext_vector_type(2)));
typedef __attribute__((address_space(1))) void as1_void;
typedef __attribute__((address_space(3))) void as3_void;

__device__ __forceinline__ u16 f2bf(float f) {
  unsigned u = __float_as_uint(f);
  u += 0x7FFF + ((u >> 16) & 1);   // RTNE
  return (u16)(u >> 16);
}

// async global->LDS, 16B per lane. LDS dest = wave-uniform base + lane*16.
__device__ __forceinline__ void async16(const u16* g, u16* l) {
  __builtin_amdgcn_global_load_lds((as1_void*)(void*)g, (as3_void*)l, 16, 0, 0);
}

// gfx9 waitcnt imm: vmcnt[3:0]=imm[3:0], exp=imm[6:4], lgkm=imm[11:8], vmcnt[5:4]=imm[15:14]
#define WAITCNT_VM8 0xF78   // vmcnt(8), lgkm/exp no-wait
#define WAITCNT_VM4 0xF74   // vmcnt(4)
#define WAITCNT_VM0 0xF70   // vmcnt(0)

// ---------------- fp32 -> bf16 cast: x then ctx, one launch ----------------
__global__ void cvt_kernel(const float* __restrict__ x, u16* __restrict__ xbf,
                           const float* __restrict__ ctx, u16* __restrict__ ctxbf) {
  int i = blockIdx.x * 256 + threadIdx.x;
  const float* in; u16* out; int j;
  if (i < 4194304) { in = x; out = xbf; j = i; }
  else if (i < 4980736) { in = ctx; out = ctxbf; j = i - 4194304; }
  else return;
  float4 v = ((const float4*)in)[j];
  ushort4 o;
  o.x = f2bf(v.x); o.y = f2bf(v.y); o.z = f2bf(v.z); o.w = f2bf(v.w);
  ((ushort4*)out)[j] = o;
}

// ---------------- all 4 weights: W[K,N] fp32 -> Wt[N,K] bf16, one launch ----
__global__ void twt_kernel(const float* __restrict__ Wq, const float* __restrict__ Wk,
                           const float* __restrict__ Wv, const float* __restrict__ Wo,
                           u16* __restrict__ WqT, u16* __restrict__ WkT,
                           u16* __restrict__ WvT, u16* __restrict__ WoT) {
  __shared__ u16 t[32][33];
  int z = blockIdx.z;
  const float* W = z == 0 ? Wq : z == 1 ? Wk : z == 2 ? Wv : Wo;
  u16* Wt = z == 0 ? WqT : z == 1 ? WkT : z == 2 ? WvT : WoT;
  int Kd = (z == 1 || z == 2) ? 768 : 1024;
  int k0 = blockIdx.y * 32;
  if (k0 >= Kd) return;
  int tx = threadIdx.x, ty = threadIdx.y;
  int n0 = blockIdx.x * 32;
#pragma unroll
  for (int i = 0; i < 4; i++)
    t[ty + i * 8][tx] = f2bf(W[(size_t)(k0 + ty + i * 8) * 1024 + n0 + tx]);
  __syncthreads();
#pragma unroll
  for (int i = 0; i < 4; i++)
    Wt[(size_t)(n0 + ty + i * 8) * Kd + k0 + tx] = t[tx][ty + i * 8];
}

// ---------------------------------------------------------------------------
// 256x256 / BK=64 / 8-wave 8-phase GEMM core (C = A * Bt^T), bf16 inputs.
// LDS: [buf][A/B][row(256)][k(64)] bf16, 3-bit XOR chunk swizzle per row.
// ---------------------------------------------------------------------------

__device__ __forceinline__ void ld_a4(const u16* Lp, int rbase, int quad,
                                      int l15, bf16x8 a[4][2]) {
  int lb = l15 & 7;
  const char* base = (const char*)Lp;
#pragma unroll
  for (int mi = 0; mi < 4; mi++)
#pragma unroll
    for (int ks = 0; ks < 2; ks++)
      a[mi][ks] = *(const bf16x8*)(base + (rbase + mi * 16 + l15) * 128 +
                                   (((ks * 4 + quad) ^ lb) << 4));
}

__device__ __forceinline__ void ld_b2(const u16* Lp, int rbase, int quad,
                                      int l15, bf16x8 b[2][2]) {
  int lb = l15 & 7;
  const char* base = (const char*)Lp;
#pragma unroll
  for (int ni = 0; ni < 2; ni++)
#pragma unroll
    for (int ks = 0; ks < 2; ks++)
      b[ni][ks] = *(const bf16x8*)(base + (rbase + ni * 16 + l15) * 128 +
                                   (((ks * 4 + quad) ^ lb) << 4));
}

__device__ __forceinline__ void mm16(bf16x8 a[4][2], bf16x8 b[2][2],
                                     float4v acc[8][4], int mh, int nh) {
  __builtin_amdgcn_s_setprio(1);
#pragma unroll
  for (int mi = 0; mi < 4; mi++)
#pragma unroll
    for (int ni = 0; ni < 2; ni++)
#pragma unroll
      for (int ks = 0; ks < 2; ks++)
        acc[mh * 4 + mi][nh * 2 + ni] = __builtin_amdgcn_mfma_f32_16x16x32_bf16(
            a[mi][ks], b[ni][ks], acc[mh * 4 + mi][nh * 2 + ni], 0, 0, 0);
  __builtin_amdgcn_s_setprio(0);
}

__device__ __forceinline__ void gemm256_core(const u16* __restrict__ A,
                                             const u16* __restrict__ Bt, int K,
                                             int m0, int n0, float4v acc[8][4]) {
  __shared__ __align__(16) u16 L[2][2][256][64];   // 128 KiB
  int tid = threadIdx.x;
  int w = tid >> 6, lane = tid & 63;
  int l15 = lane & 15, quad = lane >> 4;
  int wm = (w >> 2) * 128, wn = (w & 3) * 64;

  // staging: wave w owns rows [w*32, w*32+32) as 4 windows of 8 rows x 64 k
  // (1KB each, coalesced). lane: local row lr=lane>>3, LDS slot sl=lane&7,
  // global chunk sl^lr (3-bit XOR; (row&7)==lr since windows are 8-aligned).
  int lr = lane >> 3, sl = lane & 7;
  const u16* pA = A + (size_t)(m0 + (w << 5) + lr) * K + ((sl ^ lr) << 3);
  const u16* pB = Bt + (size_t)(n0 + (w << 5) + lr) * K + ((sl ^ lr) << 3);
  size_t r8 = (size_t)K << 3;      // +8 rows (u16 elems)
  int dofs = (w << 11) + lane * 8; // u16 offset of window 0 dest within matrix

#define STG_A(buf, t)                                                          \
  do {                                                                         \
    const u16* s = pA + (size_t)(t) * 64;                                      \
    u16* d = &L[buf][0][0][0] + dofs;                                          \
    async16(s, d);                                                             \
    async16(s + r8, d + 512);                                                  \
    async16(s + 2 * r8, d + 1024);                                             \
    async16(s + 3 * r8, d + 1536);                                             \
  } while (0)
#define STG_B(buf, t)                                                          \
  do {                                                                         \
    const u16* s = pB + (size_t)(t) * 64;                                      \
    u16* d = &L[buf][1][0][0] + dofs;                                          \
    async16(s, d);                                                             \
    async16(s + r8, d + 512);                                                  \
    async16(s + 2 * r8, d + 1024);                                             \
    async16(s + 3 * r8, d + 1536);                                             \
  } while (0)

  // prologue: tiles 0 -> buf0, 1 -> buf1 (16 loads/thread outstanding)
  STG_A(0, 0); STG_B(0, 0);
  STG_A(1, 1); STG_B(1, 1);
  __builtin_amdgcn_s_waitcnt(WAITCNT_VM8);   // tile 0 landed; tile 1 in flight
  __builtin_amdgcn_s_barrier();

  bf16x8 a[4][2], b0[2][2], b1[2][2];
  int I = K >> 7;                            // 2 K-tiles (of 64) per iteration
  for (int i = 0; i < I; ++i) {
    int st = (i + 1 < I);
    // ================= buf0 : K-tile 2i =================
    // PH1
    ld_a4(&L[0][0][0][0], wm, quad, l15, a);
    ld_b2(&L[0][1][0][0], wn, quad, l15, b0);
    if (i > 0) STG_B(1, 2 * i + 1);          // buf1 B last read PH6 of prev iter
    __builtin_amdgcn_s_barrier();
    mm16(a, b0, acc, 0, 0);
    __builtin_amdgcn_s_barrier();
    // PH2
    ld_b2(&L[0][1][0][0], wn + 32, quad, l15, b1);
    __builtin_amdgcn_s_barrier();
    mm16(a, b1, acc, 0, 1);
    __builtin_amdgcn_s_barrier();
    // PH3
    ld_a4(&L[0][0][0][0], wm + 64, quad, l15, a);
    __builtin_amdgcn_s_barrier();
    mm16(a, b1, acc, 1, 1);
    __builtin_amdgcn_s_barrier();
    // PH4
    if (st) STG_A(0, 2 * i + 2);             // buf0 A last read PH3
    __builtin_amdgcn_s_barrier();
    mm16(a, b0, acc, 1, 0);
    if (st) __builtin_amdgcn_s_waitcnt(WAITCNT_VM4);  // tile 2i+1 fully landed
    else    __builtin_amdgcn_s_waitcnt(WAITCNT_VM0);
    __builtin_amdgcn_s_barrier();
    // ================= buf1 : K-tile 2i+1 =================
    // PH5
    ld_a4(&L[1][0][0][0], wm, quad, l15, a);
    ld_b2(&L[1][1][0][0], wn, quad, l15, b0);
    if (st) STG_B(0, 2 * i + 2);             // buf0 B last read PH2
    __builtin_amdgcn_s_barrier();
    mm16(a, b0, acc, 0, 0);
    __builtin_amdgcn_s_barrier();
    // PH6
    ld_b2(&L[1][1][0][0], wn + 32, quad, l15, b1);
    __builtin_amdgcn_s_barrier();
    mm16(a, b1, acc, 0, 1);
    __builtin_amdgcn_s_barrier();
    // PH7
    ld_a4(&L[1][0][0][0], wm + 64, quad, l15, a);
    __builtin_amdgcn_s_barrier();
    mm16(a, b1, acc, 1, 1);
    __builtin_amdgcn_s_barrier();
    // PH8
    if (st) STG_A(1, 2 * i + 3);             // buf1 A last read PH7
    __builtin_amdgcn_s_barrier();
    mm16(a, b0, acc, 1, 0);
    if (st) __builtin_amdgcn_s_waitcnt(WAITCNT_VM4);  // tile 2i+2 fully landed
    __builtin_amdgcn_s_barrier();
  }
#undef STG_A
#undef STG_B
}

// ---------------- fused QKV projection GEMM (bx-partitioned, 256^2 tiles) --
// XCD swizzle: launched index -> tile index t=(bx&7)*48+bx>>3 (384 wgs, 8 XCDs)
__global__ __launch_bounds__(512, 2) void qkv_gemm8(
    const u16* __restrict__ xbf, const u16* __restrict__ ctxbf,
    const u16* __restrict__ WqT, const u16* __restrict__ WkT, const u16* __restrict__ WvT,
    u16* __restrict__ Qb, u16* __restrict__ Kbuf, u16* __restrict__ Vtb, float qscale) {
  int bx0 = blockIdx.x;
  int bx = (bx0 & 7) * 48 + (bx0 >> 3);    // bijective: 384 = 8 x 48
  const u16* A; const u16* Bt; u16* C; int K, mode, m0, n0; float scale;
  if (bx < 256)      { int t = bx;       A = xbf;   Bt = WqT; C = Qb;   K = 1024; mode = 0; scale = qscale; m0 = (t >> 2) * 256; n0 = (t & 3) * 256; }
  else if (bx < 320) { int t = bx - 256; A = ctxbf; Bt = WkT; C = Kbuf; K = 768;  mode = 0; scale = 1.0f;   m0 = (t >> 2) * 256; n0 = (t & 3) * 256; }
  else               { int t = bx - 320; A = ctxbf; Bt = WvT; C = Vtb;  K = 768;  mode = 2; scale = 1.0f;   m0 = (t >> 2) * 256; n0 = (t & 3) * 256; }

  float4v acc[8][4] = {};
  gemm256_core(A, Bt, K, m0, n0, acc);

  int tid = threadIdx.x;
  int w = tid >> 6, lane = tid & 63;
  int l15 = lane & 15, quad = lane >> 4;
  int wm = (w >> 2) * 128, wn = (w & 3) * 64;

  if (mode == 0) {
#pragma unroll
    for (int mi = 0; mi < 8; mi++) {
      int rowb = m0 + wm + mi * 16 + quad * 4;
#pragma unroll
      for (int ni = 0; ni < 4; ni++) {
        int col = n0 + wn + ni * 16 + l15;
#pragma unroll
        for (int r = 0; r < 4; r++)
          C[(size_t)(rowb + r) * 1024 + col] = f2bf(acc[mi][ni][r] * scale);
      }
    }
  } else {
#pragma unroll
    for (int mi = 0; mi < 8; mi++) {
      int rowb = m0 + wm + mi * 16 + quad * 4;
#pragma unroll
      for (int ni = 0; ni < 4; ni++) {
        int col = n0 + wn + ni * 16 + l15;
        int hh = col >> 6, dd = col & 63;
#pragma unroll
        for (int r = 0; r < 4; r++) {
          int rr = rowb + r;
          int b = rr >> 10, skv = rr & 1023;
          _Float16 hv = (_Float16)acc[mi][ni][r];
          C[((((size_t)b * 16 + hh) * 64 + dd) << 10) + skv] = __builtin_bit_cast(u16, hv);
        }
      }
    }
  }
}

// ---------------- output projection: out = attn*WoT^T + bo (fp32, 256^2) ---
// XCD swizzle: t=(bx&7)*32+bx>>3 (256 wgs, 8 XCDs)
__global__ __launch_bounds__(512, 2) void gemm_bt8(
    const u16* __restrict__ A, const u16* __restrict__ Bt,
    float* __restrict__ C, const float* __restrict__ bias) {
  int bx0 = blockIdx.x;
  int bx = (bx0 & 7) * 32 + (bx0 >> 3);    // bijective: 256 = 8 x 32
  int m0 = (bx >> 2) * 256, n0 = (bx & 3) * 256;

  float4v acc[8][4] = {};
  gemm256_core(A, Bt, 1024, m0, n0, acc);

  int tid = threadIdx.x;
  int w = tid >> 6, lane = tid & 63;
  int l15 = lane & 15, quad = lane >> 4;
  int wm = (w >> 2) * 128, wn = (w & 3) * 64;

#pragma unroll
  for (int mi = 0; mi < 8; mi++) {
    int rowb = m0 + wm + mi * 16 + quad * 4;
#pragma unroll
    for (int ni = 0; ni < 4; ni++) {
      int col = n0 + wn + ni * 16 + l15;
      float bv = bias[col];
#pragma unroll
      for (int r = 0; r < 4; r++)
        C[(size_t)(rowb + r) * 1024 + col] = acc[mi][ni][r] + bv;
    }
  }
}

// ---------------- attention v9: per (b,h), O = softmax(Q K^T) V -------------
// grid (SQ/256, B*H), block 512 (8 waves, 32 q each), launch_bounds(512,4).
// KVBLK=128: 8 iterations. LDS 64KB double-buffered, XOR-swizzled.
__global__ __launch_bounds__(512, 4) void attn_kernel(
    const u16* __restrict__ Q, const u16* __restrict__ Kb,
    const u16* __restrict__ Vt, u16* __restrict__ Oout) {
  __shared__ __align__(16) u16 lK[2][8192];   // 128kv x 64d bf16, XOR-swizzled
  __shared__ __align__(16) u16 lV[2][8192];   // 64d x 128kv f16, XOR-swizzled
  int tid = threadIdx.x, w = tid >> 6, lane = tid & 63;
  int l15 = lane & 15, quad = lane >> 4;
  int bh = blockIdx.y, b = bh >> 4, h = bh & 15;
  int q0 = blockIdx.x * 256 + w * 32;

  const u16* Qbase = Q + ((size_t)(b * 4096 + q0)) * 1024 + h * 64;
  const u16* Kbase = Kb + ((size_t)b << 20) + h * 64;
  const u16* Vbase = Vt + ((size_t)bh << 16);

  bf16x8 qf[2][2];
#pragma unroll
  for (int qt = 0; qt < 2; qt++)
#pragma unroll
    for (int c = 0; c < 2; c++)
      qf[qt][c] = *(const bf16x8*)(Qbase + (size_t)(qt * 16 + l15) * 1024 + c * 32 + quad * 8);

  int kr0 = tid >> 3, kx0 = ((tid & 7) ^ (kr0 & 7)) * 8;
  const u16* ks0 = Kbase + (size_t)kr0 * 1024 + kx0;
  const u16* ks1 = ks0 + (size_t)64 * 1024;
  int vd0 = tid >> 4, vc0 = ((tid & 15) ^ (vd0 & 15)) * 8;
  const u16* vs0 = Vbase + (size_t)vd0 * 1024 + vc0;
  const u16* vs1 = vs0 + (size_t)32 * 1024;
  int kdo0 = w * 512, kdo1 = 4096 + w * 512;

  async16(ks0, &lK[0][kdo0]); async16(ks1, &lK[0][kdo1]);
  async16(vs0, &lV[0][kdo0]); async16(vs1, &lV[0][kdo1]);
  ks0 += 131072; ks1 += 131072;
  vs0 += 128; vs1 += 128;

  float4v o[2][4] = {};
  float4v osum[2] = {};
  const half4 ones = {(_Float16)1.0f, (_Float16)1.0f, (_Float16)1.0f, (_Float16)1.0f};

  int lb = l15 & 7;
  int xk0 = ((0 + quad) ^ lb) * 16 + l15 * 128;
  int xk1 = ((4 + quad) ^ lb) * 16 + l15 * 128;
  int qh = quad >> 1, qo = (quad & 1) * 8;
  int vrow = l15 * 256 + qo;

  for (int it = 0; it < 8; ++it) {
    const char* bK = (const char*)lK + (it & 1) * 16384;
    const char* bV = (const char*)lV + (it & 1) * 16384;
    __syncthreads();
    if (it < 7) {
      int nb = (it + 1) & 1;
      async16(ks0, &lK[nb][kdo0]); async16(ks1, &lK[nb][kdo1]);
      async16(vs0, &lV[nb][kdo0]); async16(vs1, &lV[nb][kdo1]);
      ks0 += 131072; ks1 += 131072;
      vs0 += 128; vs1 += 128;
    }
#pragma unroll
    for (int ss = 0; ss < 8; ss++) {
      int sub = (ss + w) & 7;
      int sb = sub * 2048;
      float4v sv[2] = {{0.f, 0.f, 0.f, 0.f}, {0.f, 0.f, 0.f, 0.f}};
      __builtin_amdgcn_s_setprio(1);
#pragma unroll
      for (int c = 0; c < 2; c++) {
        bf16x8 kf = *(const bf16x8*)(bK + sb + (c ? xk1 : xk0));
#pragma unroll
        for (int qt = 0; qt < 2; qt++)
          sv[qt] = __builtin_amdgcn_mfma_f32_16x16x32_bf16(kf, qf[qt][c], sv[qt], 0, 0, 0);
      }
      __builtin_amdgcn_s_setprio(0);
      half4 pf[2];
#pragma unroll
      for (int qt = 0; qt < 2; qt++) {
        float e0 = exp2f(sv[qt][0]), e1 = exp2f(sv[qt][1]);
        float e2 = exp2f(sv[qt][2]), e3 = exp2f(sv[qt][3]);
        half2v p01 = __builtin_bit_cast(half2v, __builtin_amdgcn_cvt_pkrtz(e0, e1));
        half2v p23 = __builtin_bit_cast(half2v, __builtin_amdgcn_cvt_pkrtz(e2, e3));
        pf[qt] = __builtin_shufflevector(p01, p23, 0, 1, 2, 3);
        osum[qt] = __builtin_amdgcn_mfma_f32_16x16x16f16(ones, pf[qt], osum[qt], 0, 0, 0);
      }
      int vbs = vrow + (((sub * 2 + qh) ^ l15) * 16);
      __builtin_amdgcn_s_setprio(1);
#pragma unroll
      for (int dt = 0; dt < 4; dt++) {
        half4 vf = *(const half4*)(bV + dt * 4096 + vbs);
#pragma unroll
        for (int qt = 0; qt < 2; qt++)
          o[qt][dt] = __builtin_amdgcn_mfma_f32_16x16x16f16(vf, pf[qt], o[qt][dt], 0, 0, 0);
      }
      __builtin_amdgcn_s_setprio(0);
    }
  }

#pragma unroll
  for (int qt = 0; qt < 2; qt++) {
    float inv = 1.0f / osum[qt][0];
    u16* Ob = Oout + ((size_t)(b * 4096 + q0 + qt * 16 + l15)) * 1024 + h * 64 + quad * 4;
#pragma unroll
    for (int dt = 0; dt < 4; dt++) {
      ushort4 pk;
      pk.x = f2bf(o[qt][dt][0] * inv);
      pk.y = f2bf(o[qt][dt][1] * inv);
      pk.z = f2bf(o[qt][dt][2] * inv);
      pk.w = f2bf(o[qt][dt][3] * inv);
      *(ushort4*)(Ob + dt * 16) = pk;
    }
  }
}

// ---------------------------------------------------------------------------
extern "C" void kernel_launch(void* const* d_in, const int* in_sizes, int n_in,
                              void* d_out, int out_size, void* d_ws, size_t ws_size,
                              hipStream_t stream) {
  const float* x   = (const float*)d_in[0];
  const float* ctx = (const float*)d_in[1];
  const float* Wq  = (const float*)d_in[2];
  const float* Wk  = (const float*)d_in[3];
  const float* Wv  = (const float*)d_in[4];
  const float* Wo  = (const float*)d_in[5];
  const float* bo  = (const float*)d_in[6];
  float* out = (float*)d_out;

  u16* ws    = (u16*)d_ws;
  u16* xbf   = ws;                  // 16777216 elems (reused as attn_out)
  u16* ctxbf = xbf + 16777216;      // 3145728
  u16* WqT   = ctxbf + 3145728;     // 1048576
  u16* WkT   = WqT + 1048576;       // 786432
  u16* WvT   = WkT + 786432;        // 786432
  u16* WoT   = WvT + 786432;        // 1048576
  u16* Qb    = WoT + 1048576;       // 16777216
  u16* Kbuf  = Qb + 16777216;       // 4194304
  u16* Vtb   = Kbuf + 4194304;      // 4194304 (f16)  -> total ~93 MB
  if (ws_size < (size_t)48758784 * 2) return;  // workspace too small: clean fail

  cvt_kernel<<<19456, 256, 0, stream>>>(x, xbf, ctx, ctxbf);
  twt_kernel<<<dim3(32, 32, 4), dim3(32, 8), 0, stream>>>(Wq, Wk, Wv, Wo, WqT, WkT, WvT, WoT);
  // 256 Q-blocks + 64 K-blocks + 64 V-blocks, 512 threads, 8-phase schedule
  qkv_gemm8<<<dim3(384), dim3(512), 0, stream>>>(xbf, ctxbf, WqT, WkT, WvT,
                                                 Qb, Kbuf, Vtb, 0.18033688011112042f);
  // attention -> attn_out (bf16, [b, sq, h*64+d]), reusing xbf
  attn_kernel<<<dim3(16, 64), dim3(512), 0, stream>>>(Qb, Kbuf, Vtb, xbf);
  // out = attn_out*Wo + bo (fp32), 64x4 tiles of 256^2
  gemm_bt8<<<dim3(256), dim3(512), 0, stream>>>(xbf, WoT, out, bo);
}